// Round 1
// baseline (363.298 us; speedup 1.0000x reference)
//
#include <hip/hip_runtime.h>

// MultiheadAttention: bs=2, n_ctx=2048, width=1024, HEADS=16, head_dim=64, fp32 in/out.
// Pipeline: split/transpose converts -> bf16x3 QKV GEMM -> bf16 flash attention -> bf16x3 proj GEMM.

using u16 = unsigned short;
typedef __attribute__((ext_vector_type(8))) short s16x8;   // 8 bf16 = 4 VGPR (MFMA A/B frag)
typedef __attribute__((ext_vector_type(4))) float f32x4;   // MFMA C/D frag

__device__ __forceinline__ u16 f2bf(float f) {
    unsigned x = __builtin_bit_cast(unsigned, f);
    x += 0x7fffu + ((x >> 16) & 1u);            // RNE
    return (u16)(x >> 16);
}
__device__ __forceinline__ float bf2f(u16 u) {
    return __builtin_bit_cast(float, ((unsigned)u) << 16);
}

#define MFMA(a, b, c) __builtin_amdgcn_mfma_f32_16x16x32_bf16((a), (b), (c), 0, 0, 0)

// ---------------- converts ----------------

// fp32 -> (hi, lo) bf16 split, elementwise. n multiple of 4.
__global__ __launch_bounds__(256) void convert_split(const float* __restrict__ in,
                                                     u16* __restrict__ H, u16* __restrict__ L, int n) {
    int i = (blockIdx.x * 256 + threadIdx.x) * 4;
    if (i >= n) return;
    float4 v = *(const float4*)(in + i);
    u16 h0 = f2bf(v.x), h1 = f2bf(v.y), h2 = f2bf(v.z), h3 = f2bf(v.w);
    ushort4 hh = { h0, h1, h2, h3 };
    ushort4 ll = { f2bf(v.x - bf2f(h0)), f2bf(v.y - bf2f(h1)), f2bf(v.z - bf2f(h2)), f2bf(v.w - bf2f(h3)) };
    *(ushort4*)(H + i) = hh;
    *(ushort4*)(L + i) = ll;
}

// W[K][N] fp32 -> WT[N][K] bf16 hi/lo (transposed so GEMM B-fragments read contiguous K).
__global__ __launch_bounds__(256) void transpose_split(const float* __restrict__ W,
                                                       u16* __restrict__ TH, u16* __restrict__ TL,
                                                       int K, int N) {
    __shared__ float st[32][33];
    int n0 = blockIdx.x * 32, k0 = blockIdx.y * 32;
    int c = threadIdx.x & 31, r8 = threadIdx.x >> 5;
#pragma unroll
    for (int i = 0; i < 4; ++i) {
        int r = r8 + i * 8;
        st[r][c] = W[(size_t)(k0 + r) * N + n0 + c];
    }
    __syncthreads();
#pragma unroll
    for (int i = 0; i < 4; ++i) {
        int r = r8 + i * 8;
        float v = st[c][r];                       // = W[k0+c][n0+r]
        u16 h = f2bf(v);
        TH[(size_t)(n0 + r) * K + k0 + c] = h;
        TL[(size_t)(n0 + r) * K + k0 + c] = f2bf(v - bf2f(h));
    }
}

// ---------------- bf16x3 GEMM (128x128 tile, BK=32, 4 waves) ----------------
// A[M][1024] hi/lo (row-major), BT[N][1024] hi/lo (B transposed).
// EPI 0: QKV epilogue -> writes Qs (scaled 1/8), K, VT (all bf16).
// EPI 1: proj epilogue -> writes fp32 out + bias.

template <int EPI>
__global__ __launch_bounds__(256, 2) void gemm_bf16x3(
    const u16* __restrict__ AH, const u16* __restrict__ AL,
    const u16* __restrict__ BTH, const u16* __restrict__ BTL,
    const float* __restrict__ bias,
    u16* __restrict__ Qs, u16* __restrict__ Kb, u16* __restrict__ VT,
    float* __restrict__ Out) {
    const int K = 1024;
    __shared__ u16 sAh[128][40], sAl[128][40], sBh[128][40], sBl[128][40];

    int m0 = blockIdx.y * 128, n0 = blockIdx.x * 128;
    int tid = threadIdx.x, lane = tid & 63, wv = tid >> 6;
    int g = lane >> 4, c16 = lane & 15;
    int wm = wv >> 1, wn = wv & 1;

    f32x4 acc[4][4] = {};

    for (int kt = 0; kt < 32; ++kt) {
        int k0 = kt * 32;
        s16x8 ra[2], rla[2], rb[2], rlb[2];
#pragma unroll
        for (int i = 0; i < 2; ++i) {
            int cc = i * 256 + tid;
            int rr = cc >> 2, ko = (cc & 3) * 8;
            ra[i]  = *(const s16x8*)(AH  + (size_t)(m0 + rr) * K + k0 + ko);
            rla[i] = *(const s16x8*)(AL  + (size_t)(m0 + rr) * K + k0 + ko);
            rb[i]  = *(const s16x8*)(BTH + (size_t)(n0 + rr) * K + k0 + ko);
            rlb[i] = *(const s16x8*)(BTL + (size_t)(n0 + rr) * K + k0 + ko);
        }
        __syncthreads();
#pragma unroll
        for (int i = 0; i < 2; ++i) {
            int cc = i * 256 + tid;
            int rr = cc >> 2, ko = (cc & 3) * 8;
            *(s16x8*)&sAh[rr][ko] = ra[i];
            *(s16x8*)&sAl[rr][ko] = rla[i];
            *(s16x8*)&sBh[rr][ko] = rb[i];
            *(s16x8*)&sBl[rr][ko] = rlb[i];
        }
        __syncthreads();

        s16x8 ah[4], al[4], bh[4], bl[4];
#pragma unroll
        for (int mi = 0; mi < 4; ++mi) {
            ah[mi] = *(const s16x8*)&sAh[wm * 64 + mi * 16 + c16][g * 8];
            al[mi] = *(const s16x8*)&sAl[wm * 64 + mi * 16 + c16][g * 8];
        }
#pragma unroll
        for (int ni = 0; ni < 4; ++ni) {
            bh[ni] = *(const s16x8*)&sBh[wn * 64 + ni * 16 + c16][g * 8];
            bl[ni] = *(const s16x8*)&sBl[wn * 64 + ni * 16 + c16][g * 8];
        }
#pragma unroll
        for (int mi = 0; mi < 4; ++mi)
#pragma unroll
            for (int ni = 0; ni < 4; ++ni) {
                f32x4 c = acc[mi][ni];
                c = MFMA(ah[mi], bh[ni], c);
                c = MFMA(al[mi], bh[ni], c);
                c = MFMA(ah[mi], bl[ni], c);
                acc[mi][ni] = c;
            }
    }

    // epilogue. C/D layout: col = lane&15, row = 4*(lane>>4)+reg  [m89-verified]
#pragma unroll
    for (int ni = 0; ni < 4; ++ni) {
        int col = n0 + wn * 64 + ni * 16 + c16;
        float bs = bias[col];
        if (EPI == 0) {
            int h = col / 192;
            int rm = col - h * 192;
#pragma unroll
            for (int mi = 0; mi < 4; ++mi)
#pragma unroll
                for (int r = 0; r < 4; ++r) {
                    int row = m0 + wm * 64 + mi * 16 + 4 * g + r;
                    int b = row >> 11, s = row & 2047;
                    int bh16 = b * 16 + h;
                    float val = acc[mi][ni][r] + bs;
                    if (rm < 64)
                        Qs[(((size_t)bh16 * 2048 + s) << 6) + rm] = f2bf(val * 0.125f);
                    else if (rm < 128)
                        Kb[(((size_t)bh16 * 2048 + s) << 6) + rm - 64] = f2bf(val);
                    else
                        VT[((size_t)(bh16 * 64 + rm - 128)) * 2048 + s] = f2bf(val);
                }
        } else {
#pragma unroll
            for (int mi = 0; mi < 4; ++mi)
#pragma unroll
                for (int r = 0; r < 4; ++r) {
                    int row = m0 + wm * 64 + mi * 16 + 4 * g + r;
                    Out[(size_t)row * 1024 + col] = acc[mi][ni][r] + bs;
                }
        }
    }
}

// ---------------- flash attention (bf16 MFMA) ----------------
// Qs/Kb: [bh][s][64] bf16 (Q pre-scaled by 1/8). VT: [bh][64][s] bf16.
// Block = 4 independent waves; wave handles 16 q rows; KV steps of 32.
__global__ __launch_bounds__(256, 2) void attn_fwd(
    const u16* __restrict__ Qs, const u16* __restrict__ Kb, const u16* __restrict__ VT,
    u16* __restrict__ OH, u16* __restrict__ OL) {
    __shared__ u16 P[4][16][40];

    int bh = blockIdx.y, qb = blockIdx.x;
    int tid = threadIdx.x, w = tid >> 6, lane = tid & 63;
    int g = lane >> 4, c16 = lane & 15;
    size_t base = (size_t)bh * 2048 * 64;
    int q0 = qb * 64 + w * 16;

    s16x8 qf0 = *(const s16x8*)(Qs + base + (size_t)(q0 + c16) * 64 + g * 8);
    s16x8 qf1 = *(const s16x8*)(Qs + base + (size_t)(q0 + c16) * 64 + 32 + g * 8);

    f32x4 o[4] = {};
    float mo[4] = { -1e30f, -1e30f, -1e30f, -1e30f };
    float ls[4] = {};

    for (int j = 0; j < 64; ++j) {
        int kv = j * 32;
        // S tiles: A = Q (row = lane&15), B = K (col = lane&15, k-slot = channel)
        f32x4 s0 = {}, s1 = {};
        s16x8 kf;
        kf = *(const s16x8*)(Kb + base + (size_t)(kv + c16) * 64 + g * 8);       s0 = MFMA(qf0, kf, s0);
        kf = *(const s16x8*)(Kb + base + (size_t)(kv + c16) * 64 + 32 + g * 8);  s0 = MFMA(qf1, kf, s0);
        kf = *(const s16x8*)(Kb + base + (size_t)(kv + 16 + c16) * 64 + g * 8);      s1 = MFMA(qf0, kf, s1);
        kf = *(const s16x8*)(Kb + base + (size_t)(kv + 16 + c16) * 64 + 32 + g * 8); s1 = MFMA(qf1, kf, s1);

        // online softmax: row r (=4g+reg) values live in the 16 lanes sharing g
        float f[4], rs[4];
#pragma unroll
        for (int r = 0; r < 4; ++r) {
            float t = fmaxf(s0[r], s1[r]);
            t = fmaxf(t, __shfl_xor(t, 1));
            t = fmaxf(t, __shfl_xor(t, 2));
            t = fmaxf(t, __shfl_xor(t, 4));
            t = fmaxf(t, __shfl_xor(t, 8));
            float mn = fmaxf(mo[r], t);
            f[r] = __expf(mo[r] - mn);
            mo[r] = mn;
            s0[r] = __expf(s0[r] - mn);
            s1[r] = __expf(s1[r] - mn);
            float sm = s0[r] + s1[r];
            sm += __shfl_xor(sm, 1);
            sm += __shfl_xor(sm, 2);
            sm += __shfl_xor(sm, 4);
            sm += __shfl_xor(sm, 8);
            rs[r] = sm;
        }
#pragma unroll
        for (int r = 0; r < 4; ++r) {
            ls[r] = ls[r] * f[r] + rs[r];
            P[w][4 * g + r][c16] = f2bf(s0[r]);
            P[w][4 * g + r][16 + c16] = f2bf(s1[r]);
        }
        // rescale O
#pragma unroll
        for (int n = 0; n < 4; ++n)
#pragma unroll
            for (int r = 0; r < 4; ++r) o[n][r] *= f[r];

        // PV: A = P (LDS round trip; same-wave DS ordering), B = V^T rows
        s16x8 pa = *(const s16x8*)&P[w][c16][g * 8];
#pragma unroll
        for (int n = 0; n < 4; ++n) {
            s16x8 vf = *(const s16x8*)(VT + base + (size_t)(n * 16 + c16) * 2048 + kv + g * 8);
            o[n] = MFMA(pa, vf, o[n]);
        }
    }

    int b = bh >> 4, h = bh & 15;
    float inv[4];
#pragma unroll
    for (int r = 0; r < 4; ++r) inv[r] = 1.0f / ls[r];
#pragma unroll
    for (int n = 0; n < 4; ++n)
#pragma unroll
        for (int r = 0; r < 4; ++r) {
            int t = q0 + 4 * g + r;
            int col = h * 64 + n * 16 + c16;
            float val = o[n][r] * inv[r];
            u16 hh = f2bf(val);
            size_t idx = ((size_t)(b * 2048 + t)) * 1024 + col;
            OH[idx] = hh;
            OL[idx] = f2bf(val - bf2f(hh));
        }
}

// ---------------- launch ----------------

extern "C" void kernel_launch(void* const* d_in, const int* in_sizes, int n_in,
                              void* d_out, int out_size, void* d_ws, size_t ws_size,
                              hipStream_t stream) {
    const float* x     = (const float*)d_in[0];
    const float* Wqkv  = (const float*)d_in[1];
    const float* bqkv  = (const float*)d_in[2];
    const float* Wproj = (const float*)d_in[3];
    const float* bproj = (const float*)d_in[4];
    float* out = (float*)d_out;

    char* w = (char*)d_ws;
    const size_t SZ_X  = (size_t)4096 * 1024 * 2;  // 8 MiB (bf16)
    const size_t SZ_WQ = (size_t)3072 * 1024 * 2;  // 6 MiB
    const size_t SZ_WP = (size_t)1024 * 1024 * 2;  // 2 MiB
    u16* XH  = (u16*)w; w += SZ_X;
    u16* XL  = (u16*)w; w += SZ_X;
    u16* WQH = (u16*)w; w += SZ_WQ;
    u16* WQL = (u16*)w; w += SZ_WQ;
    u16* WPH = (u16*)w; w += SZ_WP;
    u16* WPL = (u16*)w; w += SZ_WP;
    u16* Q_s = (u16*)w; w += SZ_X;                  // [bh][s][64] scaled
    u16* K_b = (u16*)w; w += SZ_X;                  // [bh][s][64]
    u16* V_t = (u16*)w; w += SZ_X;                  // [bh][64][s]
    u16* OHp = (u16*)w; w += SZ_X;                  // attn out hi [4096][1024]
    u16* OLp = (u16*)w; w += SZ_X;                  // attn out lo

    convert_split<<<4096, 256, 0, stream>>>(x, XH, XL, 4096 * 1024);
    transpose_split<<<dim3(96, 32), 256, 0, stream>>>(Wqkv, WQH, WQL, 1024, 3072);
    transpose_split<<<dim3(32, 32), 256, 0, stream>>>(Wproj, WPH, WPL, 1024, 1024);
    gemm_bf16x3<0><<<dim3(24, 32), 256, 0, stream>>>(XH, XL, WQH, WQL, bqkv, Q_s, K_b, V_t, nullptr);
    attn_fwd<<<dim3(32, 32), 256, 0, stream>>>(Q_s, K_b, V_t, OHp, OLp);
    gemm_bf16x3<1><<<dim3(8, 32), 256, 0, stream>>>(OHp, OLp, WPH, WPL, bproj, nullptr, nullptr, nullptr, out);
}

// Round 2
// 214.173 us; speedup vs baseline: 1.6963x; 1.6963x over previous
//
#include <hip/hip_runtime.h>

// MultiheadAttention: bs=2, n_ctx=2048, width=1024, HEADS=16, head_dim=64, fp32 in/out.
// Pipeline: split/transpose converts -> bf16x3 QKV GEMM -> swapped-QK 32x32 flash attention -> bf16x3 proj GEMM.

using u16 = unsigned short;
typedef __attribute__((ext_vector_type(8))) short s16x8;    // 8 bf16 = 4 VGPR (MFMA A/B frag)
typedef __attribute__((ext_vector_type(4))) float f32x4;    // 16x16 MFMA C/D frag
typedef __attribute__((ext_vector_type(16))) float f32x16;  // 32x32 MFMA C/D frag

__device__ __forceinline__ u16 f2bf(float f) {
    unsigned x = __builtin_bit_cast(unsigned, f);
    x += 0x7fffu + ((x >> 16) & 1u);            // RNE
    return (u16)(x >> 16);
}
__device__ __forceinline__ float bf2f(u16 u) {
    return __builtin_bit_cast(float, ((unsigned)u) << 16);
}

#define MFMA(a, b, c)   __builtin_amdgcn_mfma_f32_16x16x32_bf16((a), (b), (c), 0, 0, 0)
#define MFMA32(a, b, c) __builtin_amdgcn_mfma_f32_32x32x16_bf16((a), (b), (c), 0, 0, 0)

// ---------------- converts ----------------

__global__ __launch_bounds__(256) void convert_split(const float* __restrict__ in,
                                                     u16* __restrict__ H, u16* __restrict__ L, int n) {
    int i = (blockIdx.x * 256 + threadIdx.x) * 4;
    if (i >= n) return;
    float4 v = *(const float4*)(in + i);
    u16 h0 = f2bf(v.x), h1 = f2bf(v.y), h2 = f2bf(v.z), h3 = f2bf(v.w);
    ushort4 hh = { h0, h1, h2, h3 };
    ushort4 ll = { f2bf(v.x - bf2f(h0)), f2bf(v.y - bf2f(h1)), f2bf(v.z - bf2f(h2)), f2bf(v.w - bf2f(h3)) };
    *(ushort4*)(H + i) = hh;
    *(ushort4*)(L + i) = ll;
}

// W[K][N] fp32 -> WT[N][K] bf16 hi/lo.
__global__ __launch_bounds__(256) void transpose_split(const float* __restrict__ W,
                                                       u16* __restrict__ TH, u16* __restrict__ TL,
                                                       int K, int N) {
    __shared__ float st[32][33];
    int n0 = blockIdx.x * 32, k0 = blockIdx.y * 32;
    int c = threadIdx.x & 31, r8 = threadIdx.x >> 5;
#pragma unroll
    for (int i = 0; i < 4; ++i) {
        int r = r8 + i * 8;
        st[r][c] = W[(size_t)(k0 + r) * N + n0 + c];
    }
    __syncthreads();
#pragma unroll
    for (int i = 0; i < 4; ++i) {
        int r = r8 + i * 8;
        float v = st[c][r];
        u16 h = f2bf(v);
        TH[(size_t)(n0 + r) * K + k0 + c] = h;
        TL[(size_t)(n0 + r) * K + k0 + c] = f2bf(v - bf2f(h));
    }
}

// ---------------- bf16x3 GEMM (128x128 tile, BK=32, 4 waves) ----------------
// EPI 0: QKV epilogue -> Qs (scaled 1/8) [bh][s][64], K [bh][s][64], Vp (sigma-permuted) bf16.
// EPI 1: proj epilogue -> fp32 out + bias.

template <int EPI>
__global__ __launch_bounds__(256, 2) void gemm_bf16x3(
    const u16* __restrict__ AH, const u16* __restrict__ AL,
    const u16* __restrict__ BTH, const u16* __restrict__ BTL,
    const float* __restrict__ bias,
    u16* __restrict__ Qs, u16* __restrict__ Kb, u16* __restrict__ Vp,
    float* __restrict__ Out) {
    const int K = 1024;
    __shared__ u16 sAh[128][40], sAl[128][40], sBh[128][40], sBl[128][40];

    int m0 = blockIdx.y * 128, n0 = blockIdx.x * 128;
    int tid = threadIdx.x, lane = tid & 63, wv = tid >> 6;
    int g = lane >> 4, c16 = lane & 15;
    int wm = wv >> 1, wn = wv & 1;

    f32x4 acc[4][4] = {};

    for (int kt = 0; kt < 32; ++kt) {
        int k0 = kt * 32;
        s16x8 ra[2], rla[2], rb[2], rlb[2];
#pragma unroll
        for (int i = 0; i < 2; ++i) {
            int cc = i * 256 + tid;
            int rr = cc >> 2, ko = (cc & 3) * 8;
            ra[i]  = *(const s16x8*)(AH  + (size_t)(m0 + rr) * K + k0 + ko);
            rla[i] = *(const s16x8*)(AL  + (size_t)(m0 + rr) * K + k0 + ko);
            rb[i]  = *(const s16x8*)(BTH + (size_t)(n0 + rr) * K + k0 + ko);
            rlb[i] = *(const s16x8*)(BTL + (size_t)(n0 + rr) * K + k0 + ko);
        }
        __syncthreads();
#pragma unroll
        for (int i = 0; i < 2; ++i) {
            int cc = i * 256 + tid;
            int rr = cc >> 2, ko = (cc & 3) * 8;
            *(s16x8*)&sAh[rr][ko] = ra[i];
            *(s16x8*)&sAl[rr][ko] = rla[i];
            *(s16x8*)&sBh[rr][ko] = rb[i];
            *(s16x8*)&sBl[rr][ko] = rlb[i];
        }
        __syncthreads();

        s16x8 ah[4], al[4], bh[4], bl[4];
#pragma unroll
        for (int mi = 0; mi < 4; ++mi) {
            ah[mi] = *(const s16x8*)&sAh[wm * 64 + mi * 16 + c16][g * 8];
            al[mi] = *(const s16x8*)&sAl[wm * 64 + mi * 16 + c16][g * 8];
        }
#pragma unroll
        for (int ni = 0; ni < 4; ++ni) {
            bh[ni] = *(const s16x8*)&sBh[wn * 64 + ni * 16 + c16][g * 8];
            bl[ni] = *(const s16x8*)&sBl[wn * 64 + ni * 16 + c16][g * 8];
        }
#pragma unroll
        for (int mi = 0; mi < 4; ++mi)
#pragma unroll
            for (int ni = 0; ni < 4; ++ni) {
                f32x4 c = acc[mi][ni];
                c = MFMA(ah[mi], bh[ni], c);
                c = MFMA(al[mi], bh[ni], c);
                c = MFMA(ah[mi], bl[ni], c);
                acc[mi][ni] = c;
            }
    }

    // C/D layout: col = lane&15, row = 4*(lane>>4)+reg
#pragma unroll
    for (int ni = 0; ni < 4; ++ni) {
        int col = n0 + wn * 64 + ni * 16 + c16;
        float bs = bias[col];
        if (EPI == 0) {
            int h = col / 192;
            int rm = col - h * 192;
#pragma unroll
            for (int mi = 0; mi < 4; ++mi)
#pragma unroll
                for (int r = 0; r < 4; ++r) {
                    int row = m0 + wm * 64 + mi * 16 + 4 * g + r;
                    int b = row >> 11, s = row & 2047;
                    int bh16 = b * 16 + h;
                    float val = acc[mi][ni][r] + bs;
                    if (rm < 64)
                        Qs[(((size_t)bh16 * 2048 + s) << 6) + rm] = f2bf(val * 0.125f);
                    else if (rm < 128)
                        Kb[(((size_t)bh16 * 2048 + s) << 6) + rm - 64] = f2bf(val);
                    else {
                        // sigma-permuted V: Vp[bh][s/16][d][m], kv = 16*(s/16)+sigma(m),
                        // sigma(m) = (m&3) + 8*((m>>2)&1) + 4*(m>>3)
                        int d = rm - 128;
                        int kg = s >> 4, k16 = s & 15;
                        int mm = (k16 & 3) | (((k16 >> 3) & 1) << 2) | (((k16 >> 2) & 1) << 3);
                        Vp[(((size_t)bh16 * 128 + kg) * 64 + d) * 16 + mm] = f2bf(val);
                    }
                }
        } else {
#pragma unroll
            for (int mi = 0; mi < 4; ++mi)
#pragma unroll
                for (int r = 0; r < 4; ++r) {
                    int row = m0 + wm * 64 + mi * 16 + 4 * g + r;
                    Out[(size_t)row * 1024 + col] = acc[mi][ni][r] + bs;
                }
        }
    }
}

// ---------------- flash attention, swapped-QK 32x32 MFMA, no LDS ----------------
// S = mfma32(A=K, B=Q): lane holds q = lane&31, s[r] = S[kv0 + crow(r,h)][q],
// crow(r,h) = (r&3) + 8*(r>>2) + 4*h, h = lane>>5.  Softmax is in-lane + 1 shfl_xor(32).
// PV: A-frag elem e = exp'd s[e] (kv-half 0) / s[8+e] (half 1); V loaded sigma-permuted
// so B-frag matches the same kv ordering. O: o[n][r] = O[q0+crow(r,h)][n*32 + (lane&31)].
__global__ __launch_bounds__(256, 2) void attn_fwd(
    const u16* __restrict__ Qs, const u16* __restrict__ Kb, const u16* __restrict__ Vp,
    u16* __restrict__ OH, u16* __restrict__ OL) {
    int id = blockIdx.x;
    int xcd = id & 7, li = id >> 3;          // 4 heads per XCD -> K/V (2MB) stays L2-resident
    int bh = xcd * 4 + (li >> 4);
    int qb = li & 15;
    int tid = threadIdx.x, w = tid >> 6, lane = tid & 63;
    int l31 = lane & 31, h = lane >> 5;
    int q0 = (qb * 4 + w) * 32;

    size_t base = (size_t)bh * 2048 * 64;
    size_t vbase = (size_t)bh * 128 * 64 * 16;

    const u16* qp = Qs + base + (size_t)(q0 + l31) * 64 + 8 * h;
    s16x8 qf0 = *(const s16x8*)(qp);
    s16x8 qf1 = *(const s16x8*)(qp + 16);
    s16x8 qf2 = *(const s16x8*)(qp + 32);
    s16x8 qf3 = *(const s16x8*)(qp + 48);

    const u16* kp = Kb + base + (size_t)l31 * 64 + 8 * h;
    const u16* vb = Vp + vbase + (size_t)l31 * 16 + 8 * h;

    f32x16 o0 = {}, o1 = {};
    float m = -1e30f, ls = 0.f;

    s16x8 ka0, ka1, ka2, ka3, kb0, kb1, kb2, kb3;
    ka0 = *(const s16x8*)(kp);
    ka1 = *(const s16x8*)(kp + 16);
    ka2 = *(const s16x8*)(kp + 32);
    ka3 = *(const s16x8*)(kp + 48);

    auto step = [&](s16x8& c0, s16x8& c1, s16x8& c2, s16x8& c3,
                    s16x8& n0, s16x8& n1, s16x8& n2, s16x8& n3,
                    int kv, int kvn) {
        // V for this tile (latency hidden under S-MFMAs + softmax)
        const u16* vp = vb + (size_t)(kv >> 4) * 1024;
        s16x8 v00 = *(const s16x8*)(vp);          // n=0, kv-half 0
        s16x8 v10 = *(const s16x8*)(vp + 512);    // n=1, kv-half 0
        s16x8 v01 = *(const s16x8*)(vp + 1024);   // n=0, kv-half 1
        s16x8 v11 = *(const s16x8*)(vp + 1536);   // n=1, kv-half 1

        f32x16 s = {};
        s = MFMA32(c0, qf0, s);
        s = MFMA32(c1, qf1, s);
        s = MFMA32(c2, qf2, s);
        s = MFMA32(c3, qf3, s);

        // prefetch next K tile
        const u16* kpn = kp + (size_t)kvn * 64;
        n0 = *(const s16x8*)(kpn);
        n1 = *(const s16x8*)(kpn + 16);
        n2 = *(const s16x8*)(kpn + 32);
        n3 = *(const s16x8*)(kpn + 48);

        // in-lane max over 16, then cross-half
        float pmax = s[0];
#pragma unroll
        for (int r = 1; r < 16; ++r) pmax = fmaxf(pmax, s[r]);
        pmax = fmaxf(pmax, __shfl_xor(pmax, 32));

        if (!__all(pmax <= m + 8.f)) {          // defer-max (T13)
            float mn = fmaxf(m, pmax);
            float f = __expf(m - mn);
            m = mn;
            ls *= f;
#pragma unroll
            for (int r = 0; r < 16; ++r) {
                float fb = __shfl(f, (r & 3) + 8 * (r >> 2) + 4 * h);
                o0[r] *= fb;
                o1[r] *= fb;
            }
        }

        float sm = 0.f;
        u16 pb[16];
#pragma unroll
        for (int r = 0; r < 16; ++r) {
            float e = __expf(s[r] - m);
            sm += e;
            pb[r] = f2bf(e);
        }
        sm += __shfl_xor(sm, 32);
        ls += sm;

        s16x8 pa0, pa1;
#pragma unroll
        for (int e = 0; e < 8; ++e) {
            pa0[e] = (short)pb[e];
            pa1[e] = (short)pb[8 + e];
        }

        o0 = MFMA32(pa0, v00, o0);
        o0 = MFMA32(pa1, v01, o0);
        o1 = MFMA32(pa0, v10, o1);
        o1 = MFMA32(pa1, v11, o1);
    };

    for (int j = 0; j < 64; j += 2) {
        step(ka0, ka1, ka2, ka3, kb0, kb1, kb2, kb3, j * 32, (j + 1) * 32);
        step(kb0, kb1, kb2, kb3, ka0, ka1, ka2, ka3, (j + 1) * 32, ((j + 2) & 63) * 32);
    }

    int b = bh >> 4, hh = bh & 15;
    float inv = 1.0f / ls;
#pragma unroll
    for (int r = 0; r < 16; ++r) {
        int cr = (r & 3) + 8 * (r >> 2) + 4 * h;
        float fb = __shfl(inv, cr);
        int row = q0 + cr;
        size_t idx = ((size_t)(b * 2048 + row)) * 1024 + hh * 64 + l31;
        float v0 = o0[r] * fb, v1 = o1[r] * fb;
        u16 h0 = f2bf(v0);
        OH[idx] = h0;
        OL[idx] = f2bf(v0 - bf2f(h0));
        u16 h1 = f2bf(v1);
        OH[idx + 32] = h1;
        OL[idx + 32] = f2bf(v1 - bf2f(h1));
    }
}

// ---------------- launch ----------------

extern "C" void kernel_launch(void* const* d_in, const int* in_sizes, int n_in,
                              void* d_out, int out_size, void* d_ws, size_t ws_size,
                              hipStream_t stream) {
    const float* x     = (const float*)d_in[0];
    const float* Wqkv  = (const float*)d_in[1];
    const float* bqkv  = (const float*)d_in[2];
    const float* Wproj = (const float*)d_in[3];
    const float* bproj = (const float*)d_in[4];
    float* out = (float*)d_out;

    char* w = (char*)d_ws;
    const size_t SZ_X  = (size_t)4096 * 1024 * 2;  // 8 MiB (bf16)
    const size_t SZ_WQ = (size_t)3072 * 1024 * 2;
    const size_t SZ_WP = (size_t)1024 * 1024 * 2;
    u16* XH  = (u16*)w; w += SZ_X;
    u16* XL  = (u16*)w; w += SZ_X;
    u16* WQH = (u16*)w; w += SZ_WQ;
    u16* WQL = (u16*)w; w += SZ_WQ;
    u16* WPH = (u16*)w; w += SZ_WP;
    u16* WPL = (u16*)w; w += SZ_WP;
    u16* Q_s = (u16*)w; w += SZ_X;                  // [bh][s][64] scaled
    u16* K_b = (u16*)w; w += SZ_X;                  // [bh][s][64]
    u16* V_p = (u16*)w; w += SZ_X;                  // [bh][s/16][64][16] sigma-permuted
    u16* OHp = (u16*)w; w += SZ_X;                  // attn out hi [4096][1024]
    u16* OLp = (u16*)w; w += SZ_X;                  // attn out lo

    convert_split<<<4096, 256, 0, stream>>>(x, XH, XL, 4096 * 1024);
    transpose_split<<<dim3(96, 32), 256, 0, stream>>>(Wqkv, WQH, WQL, 1024, 3072);
    transpose_split<<<dim3(32, 32), 256, 0, stream>>>(Wproj, WPH, WPL, 1024, 1024);
    gemm_bf16x3<0><<<dim3(24, 32), 256, 0, stream>>>(XH, XL, WQH, WQL, bqkv, Q_s, K_b, V_p, nullptr);
    attn_fwd<<<512, 256, 0, stream>>>(Q_s, K_b, V_p, OHp, OLp);
    gemm_bf16x3<1><<<dim3(8, 32), 256, 0, stream>>>(OHp, OLp, WPH, WPL, bproj, nullptr, nullptr, nullptr, out);
}